// Round 1
// baseline (770.428 us; speedup 1.0000x reference)
//
#include <hip/hip_runtime.h>
#include <hip/hip_bf16.h>
#include <cstddef>

#define T_TOK 1024
#define HDIM  2048
#define NEXP  64
#define IDIM  768
#define TOPK  8

using f32x4 = __attribute__((ext_vector_type(4))) float;
using s16x8 = __attribute__((ext_vector_type(8))) short;
using s16x4 = __attribute__((ext_vector_type(4))) short;

// ---- workspace layout (bytes) ----
static constexpr size_t XBF_OFF = 0;                                   // bf16 X: 4 MiB
static constexpr size_t CNT_OFF = (size_t)T_TOK * HDIM * 2;            // 64 ints
static constexpr size_t OFF_OFF = CNT_OFF + 256;                       // 65 ints
static constexpr size_t TOK_OFF = CNT_OFF + 1024;                      // 64*1024 ints
static constexpr size_t WT_OFF  = TOK_OFF + (size_t)NEXP * T_TOK * 4;  // 64*1024 floats
static constexpr size_t HH_OFF  = WT_OFF  + (size_t)NEXP * T_TOK * 4;  // 8192*768 bf16 = 12 MiB
// total ~16.5 MiB

__device__ __forceinline__ short f2bf(float f) {
  union { __hip_bfloat16 b; short s; } u;
  u.b = __float2bfloat16(f);
  return u.s;
}

// ---------------- x fp32 -> bf16 ----------------
__global__ __launch_bounds__(256) void convert_x_kernel(
    const float* __restrict__ X, __hip_bfloat16* __restrict__ Xb) {
  const int i = (blockIdx.x * 256 + threadIdx.x) * 8;
  f32x4 a = *(const f32x4*)(X + i);
  f32x4 b = *(const f32x4*)(X + i + 4);
  union { short h[8]; int4 q; } u;
#pragma unroll
  for (int c = 0; c < 4; ++c) { u.h[c] = f2bf(a[c]); u.h[4 + c] = f2bf(b[c]); }
  *(int4*)((char*)Xb + (size_t)i * 2) = u.q;
}

// ---------------- router ----------------
__global__ __launch_bounds__(256) void router_kernel(
    const float* __restrict__ X, const float* __restrict__ GW,
    int* __restrict__ cnt, int* __restrict__ tokl, float* __restrict__ wtl) {
  __shared__ float xs[HDIM];
  __shared__ float lg[NEXP];
  const int t = blockIdx.x;
  const int tid = threadIdx.x;
  const f32x4* xr = (const f32x4*)(X + (size_t)t * HDIM);
#pragma unroll
  for (int i = 0; i < 2; ++i) {
    f32x4 v = xr[tid + i * 256];
    *(f32x4*)&xs[(tid + i * 256) * 4] = v;
  }
  __syncthreads();
  const int wid = tid >> 6, lane = tid & 63;
  for (int ee = 0; ee < 16; ++ee) {
    const int e = wid * 16 + ee;
    const float* g = GW + (size_t)e * HDIM;
    float acc = 0.f;
    for (int i = lane; i < HDIM; i += 64) acc += xs[i] * g[i];
#pragma unroll
    for (int s = 32; s; s >>= 1) acc += __shfl_xor(acc, s);
    if (lane == 0) lg[e] = acc;
  }
  __syncthreads();
  if (tid < 64) {
    const float v = lg[tid];
    float m = v;
#pragma unroll
    for (int s = 32; s; s >>= 1) m = fmaxf(m, __shfl_xor(m, s));
    const float p = expf(v - m);
    float den = p;
#pragma unroll
    for (int s = 32; s; s >>= 1) den += __shfl_xor(den, s);
    float work = p / den;           // softmax prob for expert `tid`
    float my_v = 0.f; int my_e = 0;
    float topsum = 0.f;
#pragma unroll
    for (int k = 0; k < TOPK; ++k) {
      float mv = work;
#pragma unroll
      for (int s = 32; s; s >>= 1) mv = fmaxf(mv, __shfl_xor(mv, s));
      unsigned long long ball = __ballot(work == mv);
      const int idx = __ffsll(ball) - 1;   // lowest index on ties (matches lax.top_k)
      topsum += mv;
      if (tid == k) { my_v = mv; my_e = idx; }
      if (tid == idx) work = -1.f;
    }
    if (tid < TOPK) {
      const float w = my_v / topsum;       // renormalized routing weight
      const int slot = atomicAdd(&cnt[my_e], 1);
      tokl[my_e * T_TOK + slot] = t;
      wtl[my_e * T_TOK + slot] = w;
    }
  }
}

// ---------------- prefix scan ----------------
__global__ void scan_kernel(const int* __restrict__ cnt, int* __restrict__ offs) {
  if (threadIdx.x == 0) {
    int a = 0;
    for (int e = 0; e < NEXP; ++e) { offs[e] = a; a += cnt[e]; }
    offs[NEXP] = a;
  }
}

// ---------------- gate+up GEMM + SwiGLU (BM=128, BN=64, BK=32) ----------------
__global__ __launch_bounds__(256, 2) void gateup_kernel(
    const __hip_bfloat16* __restrict__ Xb,
    const float* __restrict__ WG, const float* __restrict__ WU,
    const int* __restrict__ cnt, const int* __restrict__ offs,
    const int* __restrict__ tokl, const float* __restrict__ wtl,
    __hip_bfloat16* __restrict__ Hh) {
  const int e  = blockIdx.z;
  const int ti = blockIdx.y;
  const int nj = blockIdx.x;
  const int ne = cnt[e];
  if (ti * 128 >= ne) return;
  const int nrows = min(128, ne - ti * 128);
  const int base  = offs[e];
  const int nb    = nj * 64;
  const int tid   = threadIdx.x;
  const int lane  = tid & 63;
  const int wid   = tid >> 6;
  const int wrow  = (wid >> 1) * 64;
  const int wcol  = (wid & 1) * 32;

  __shared__ __align__(16) char sA[2][128 * 32 * 2];      // 8 KiB each, XOR-swizzled rows
  __shared__ __align__(16) char sB[2][2][32 * 64 * 2];    // [buf][gate/up], k-grouped layout
  __shared__ float sWt[128];

  // A staging: thread -> (row, half of 32 k's)
  const int arow  = tid >> 1;
  const int ahalf = tid & 1;
  const int areff = min(arow, nrows - 1);
  const int atok  = tokl[e * T_TOK + ti * 128 + areff];
  const __hip_bfloat16* aptr = Xb + (size_t)atok * HDIM + ahalf * 16;

  // B staging: half the threads per matrix; (kg 0..7, nq 0..15) -> 4x4 fp32 block
  const int mat = tid >> 7;
  const int pp  = tid & 127;
  const int kg  = pp >> 4;
  const int nq  = pp & 15;
  const float* wptr = (mat ? WU : WG) + (size_t)e * HDIM * IDIM
                      + (size_t)(kg * 4) * IDIM + nb + nq * 4;

  if (tid < 128) sWt[tid] = (tid < nrows) ? wtl[e * T_TOK + ti * 128 + tid] : 0.f;

  f32x4 accg[4][2], accu[4][2];
#pragma unroll
  for (int i = 0; i < 4; ++i)
#pragma unroll
    for (int j = 0; j < 2; ++j)
#pragma unroll
      for (int r = 0; r < 4; ++r) { accg[i][j][r] = 0.f; accu[i][j][r] = 0.f; }

  int4 rA0, rA1;
  f32x4 rB0, rB1, rB2, rB3;

  auto load_regs = [&](int ks) {
    const int kb = ks * 32;
    rA0 = *(const int4*)(aptr + kb);
    rA1 = *(const int4*)(aptr + kb + 8);
    const float* wp = wptr + (size_t)kb * IDIM;
    rB0 = *(const f32x4*)(wp);
    rB1 = *(const f32x4*)(wp + IDIM);
    rB2 = *(const f32x4*)(wp + 2 * IDIM);
    rB3 = *(const f32x4*)(wp + 3 * IDIM);
  };

  auto write_lds = [&](int buf) {
    const int abase = arow * 64 + ahalf * 32;
    const int sw = (arow & 7) << 4;
    *(int4*)(sA[buf] + ((abase) ^ sw))      = rA0;
    *(int4*)(sA[buf] + ((abase + 16) ^ sw)) = rA1;
    union { short h[16]; int4 q[2]; } u;
#pragma unroll
    for (int c = 0; c < 4; ++c) {
      u.h[c * 4 + 0] = f2bf(rB0[c]);
      u.h[c * 4 + 1] = f2bf(rB1[c]);
      u.h[c * 4 + 2] = f2bf(rB2[c]);
      u.h[c * 4 + 3] = f2bf(rB3[c]);
    }
    char* bb = sB[buf][mat] + (kg * 64 + nq * 4) * 8;
    *(int4*)(bb)      = u.q[0];
    *(int4*)(bb + 16) = u.q[1];
  };

  auto compute = [&](int buf) {
    s16x8 af[4];
#pragma unroll
    for (int mi = 0; mi < 4; ++mi) {
      const int r = wrow + mi * 16 + (lane & 15);
      const int addr = (r * 64 + (lane >> 4) * 16) ^ ((r & 7) << 4);
      af[mi] = *(const s16x8*)(sA[buf] + addr);
    }
    s16x8 bg[2], bu[2];
#pragma unroll
    for (int ni = 0; ni < 2; ++ni) {
      const int col = wcol + ni * 16 + (lane & 15);
      const int g2  = (lane >> 4) * 2;
      const char* pg = sB[buf][0];
      const char* pu = sB[buf][1];
      s16x4 glo = *(const s16x4*)(pg + (g2 * 64 + col) * 8);
      s16x4 ghi = *(const s16x4*)(pg + ((g2 + 1) * 64 + col) * 8);
      s16x4 ulo = *(const s16x4*)(pu + (g2 * 64 + col) * 8);
      s16x4 uhi = *(const s16x4*)(pu + ((g2 + 1) * 64 + col) * 8);
#pragma unroll
      for (int j = 0; j < 4; ++j) {
        bg[ni][j] = glo[j]; bg[ni][j + 4] = ghi[j];
        bu[ni][j] = ulo[j]; bu[ni][j + 4] = uhi[j];
      }
    }
#pragma unroll
    for (int mi = 0; mi < 4; ++mi)
#pragma unroll
      for (int ni = 0; ni < 2; ++ni) {
        accg[mi][ni] = __builtin_amdgcn_mfma_f32_16x16x32_bf16(af[mi], bg[ni], accg[mi][ni], 0, 0, 0);
        accu[mi][ni] = __builtin_amdgcn_mfma_f32_16x16x32_bf16(af[mi], bu[ni], accu[mi][ni], 0, 0, 0);
      }
  };

  load_regs(0);
  write_lds(0);
  __syncthreads();
  int cur = 0;
  for (int ks = 0; ks < HDIM / 32; ++ks) {
    const bool more = (ks + 1) < HDIM / 32;
    if (more) load_regs(ks + 1);   // issue next tile's global loads early (T14)
    compute(cur);
    if (more) write_lds(cur ^ 1);  // other buffer: no barrier needed vs compute(cur)
    __syncthreads();
    cur ^= 1;
  }

  const int r0 = wrow + ((lane >> 4) << 2);
  const int c0 = nb + wcol + (lane & 15);
#pragma unroll
  for (int mi = 0; mi < 4; ++mi)
#pragma unroll
    for (int ni = 0; ni < 2; ++ni)
#pragma unroll
      for (int r = 0; r < 4; ++r) {
        const int lrow = r0 + mi * 16 + r;
        if (lrow < nrows) {
          const float g  = accg[mi][ni][r];
          const float uu = accu[mi][ni][r];
          const float h  = (g / (1.f + __expf(-g))) * uu * sWt[lrow];  // silu(g)*u, pre-scaled by route weight
          Hh[(size_t)(base + ti * 128 + lrow) * IDIM + c0 + ni * 16] = __float2bfloat16(h);
        }
      }
}

// ---------------- down GEMM + scatter (BM=128, BN=128, BK=32) ----------------
__global__ __launch_bounds__(256, 2) void down_kernel(
    const __hip_bfloat16* __restrict__ Hh,
    const float* __restrict__ WD,
    const int* __restrict__ cnt, const int* __restrict__ offs,
    const int* __restrict__ tokl,
    float* __restrict__ Out) {
  const int e  = blockIdx.z;
  const int ti = blockIdx.y;
  const int nj = blockIdx.x;
  const int ne = cnt[e];
  if (ti * 128 >= ne) return;
  const int nrows = min(128, ne - ti * 128);
  const int base  = offs[e];
  const int nb    = nj * 128;
  const int tid   = threadIdx.x;
  const int lane  = tid & 63;
  const int wid   = tid >> 6;
  const int wrow  = (wid >> 1) * 64;
  const int wcol  = (wid & 1) * 64;

  __shared__ __align__(16) char sA[2][128 * 32 * 2];
  __shared__ __align__(16) char sB[2][8 * 128 * 4 * 2];
  __shared__ int sTok[128];

  const int arow  = tid >> 1;
  const int ahalf = tid & 1;
  const int areff = min(arow, nrows - 1);
  const __hip_bfloat16* aptr = Hh + (size_t)(base + ti * 128 + areff) * IDIM + ahalf * 16;

  const int kg = tid >> 5;
  const int nq = tid & 31;
  const float* wptr = WD + (size_t)e * IDIM * HDIM + (size_t)(kg * 4) * HDIM + nb + nq * 4;

  if (tid < 128) sTok[tid] = tokl[e * T_TOK + ti * 128 + min(tid, nrows - 1)];

  f32x4 acc[4][4];
#pragma unroll
  for (int i = 0; i < 4; ++i)
#pragma unroll
    for (int j = 0; j < 4; ++j)
#pragma unroll
      for (int r = 0; r < 4; ++r) acc[i][j][r] = 0.f;

  int4 rA0, rA1;
  f32x4 rB0, rB1, rB2, rB3;

  auto load_regs = [&](int ks) {
    const int kb = ks * 32;
    rA0 = *(const int4*)(aptr + kb);
    rA1 = *(const int4*)(aptr + kb + 8);
    const float* wp = wptr + (size_t)kb * HDIM;
    rB0 = *(const f32x4*)(wp);
    rB1 = *(const f32x4*)(wp + HDIM);
    rB2 = *(const f32x4*)(wp + 2 * HDIM);
    rB3 = *(const f32x4*)(wp + 3 * HDIM);
  };

  auto write_lds = [&](int buf) {
    const int abase = arow * 64 + ahalf * 32;
    const int sw = (arow & 7) << 4;
    *(int4*)(sA[buf] + ((abase) ^ sw))      = rA0;
    *(int4*)(sA[buf] + ((abase + 16) ^ sw)) = rA1;
    union { short h[16]; int4 q[2]; } u;
#pragma unroll
    for (int c = 0; c < 4; ++c) {
      u.h[c * 4 + 0] = f2bf(rB0[c]);
      u.h[c * 4 + 1] = f2bf(rB1[c]);
      u.h[c * 4 + 2] = f2bf(rB2[c]);
      u.h[c * 4 + 3] = f2bf(rB3[c]);
    }
    char* bb = sB[buf] + (kg * 128 + nq * 4) * 8;
    *(int4*)(bb)      = u.q[0];
    *(int4*)(bb + 16) = u.q[1];
  };

  auto compute = [&](int buf) {
    s16x8 af[4];
#pragma unroll
    for (int mi = 0; mi < 4; ++mi) {
      const int r = wrow + mi * 16 + (lane & 15);
      const int addr = (r * 64 + (lane >> 4) * 16) ^ ((r & 7) << 4);
      af[mi] = *(const s16x8*)(sA[buf] + addr);
    }
    s16x8 bf[4];
#pragma unroll
    for (int ni = 0; ni < 4; ++ni) {
      const int col = wcol + ni * 16 + (lane & 15);
      const int g2  = (lane >> 4) * 2;
      s16x4 lo = *(const s16x4*)(sB[buf] + (g2 * 128 + col) * 8);
      s16x4 hi = *(const s16x4*)(sB[buf] + ((g2 + 1) * 128 + col) * 8);
#pragma unroll
      for (int j = 0; j < 4; ++j) { bf[ni][j] = lo[j]; bf[ni][j + 4] = hi[j]; }
    }
#pragma unroll
    for (int mi = 0; mi < 4; ++mi)
#pragma unroll
      for (int ni = 0; ni < 4; ++ni)
        acc[mi][ni] = __builtin_amdgcn_mfma_f32_16x16x32_bf16(af[mi], bf[ni], acc[mi][ni], 0, 0, 0);
  };

  load_regs(0);
  write_lds(0);
  __syncthreads();
  int cur = 0;
  for (int ks = 0; ks < IDIM / 32; ++ks) {
    const bool more = (ks + 1) < IDIM / 32;
    if (more) load_regs(ks + 1);
    compute(cur);
    if (more) write_lds(cur ^ 1);
    __syncthreads();
    cur ^= 1;
  }

  const int r0 = wrow + ((lane >> 4) << 2);
  const int c0 = nb + wcol + (lane & 15);
#pragma unroll
  for (int mi = 0; mi < 4; ++mi)
#pragma unroll
    for (int ni = 0; ni < 4; ++ni)
#pragma unroll
      for (int r = 0; r < 4; ++r) {
        const int lrow = r0 + mi * 16 + r;
        if (lrow < nrows) {
          const int tkn = sTok[lrow];
          atomicAdd(&Out[(size_t)tkn * HDIM + c0 + ni * 16], acc[mi][ni][r]);
        }
      }
}

extern "C" void kernel_launch(void* const* d_in, const int* in_sizes, int n_in,
                              void* d_out, int out_size, void* d_ws, size_t ws_size,
                              hipStream_t stream) {
  (void)in_sizes; (void)n_in; (void)ws_size;
  const float* X  = (const float*)d_in[0];
  const float* GW = (const float*)d_in[1];
  const float* WG = (const float*)d_in[2];
  const float* WU = (const float*)d_in[3];
  const float* WD = (const float*)d_in[4];
  float* Out = (float*)d_out;
  char* ws = (char*)d_ws;

  __hip_bfloat16* Xb = (__hip_bfloat16*)(ws + XBF_OFF);
  int*   cnt  = (int*)(ws + CNT_OFF);
  int*   offs = (int*)(ws + OFF_OFF);
  int*   tokl = (int*)(ws + TOK_OFF);
  float* wtl  = (float*)(ws + WT_OFF);
  __hip_bfloat16* Hh = (__hip_bfloat16*)(ws + HH_OFF);

  hipMemsetAsync(cnt, 0, NEXP * sizeof(int), stream);
  hipMemsetAsync(d_out, 0, (size_t)out_size * sizeof(float), stream);

  convert_x_kernel<<<(T_TOK * HDIM) / (256 * 8), 256, 0, stream>>>(X, Xb);
  router_kernel<<<T_TOK, 256, 0, stream>>>(X, GW, cnt, tokl, wtl);
  scan_kernel<<<1, 64, 0, stream>>>(cnt, offs);
  gateup_kernel<<<dim3(IDIM / 64, T_TOK / 128, NEXP), 256, 0, stream>>>(
      Xb, WG, WU, cnt, offs, tokl, wtl, Hh);
  down_kernel<<<dim3(HDIM / 128, T_TOK / 128, NEXP), 256, 0, stream>>>(
      Hh, WD, cnt, offs, tokl, Out);
}